// Round 11
// baseline (667.477 us; speedup 1.0000x reference)
//
#include <hip/hip_runtime.h>
#include <hip/hip_bf16.h>
#include <cstdint>
#include <cstddef>

#define B_ROWS 4096
#define D_DIM  256
#define TWOB   8192
static constexpr float kScale = 2.8853900817779268f; // log2(e)/TEMPERATURE, T=0.5

typedef __bf16 bf16_t;
typedef __bf16 bf16x4 __attribute__((ext_vector_type(4)));
typedef __bf16 bf16x8 __attribute__((ext_vector_type(8)));
typedef float  f32x4  __attribute__((ext_vector_type(4)));

// ---- workspace layout ----
#define WS_Z    0ull                                  // bf16 [8192][256], PLAIN row-major
#define WS_KEYS ((size_t)TWOB * D_DIM * 2)            // i32 [8192]
#define WS_DEN  (WS_KEYS + (size_t)TWOB * 4)          // f32 [8192]
#define WS_PAIR (WS_DEN + (size_t)TWOB * 4)           // f32 [4096]
#define WS_CNT  (WS_PAIR + (size_t)B_ROWS * 4)        // i32 [1]

// ---------------- kernel 1: normalize + bf16 store + keys + zeroing + pair dots ----------------
__global__ __launch_bounds__(256) void prep_kernel(
    const float* __restrict__ emb_i, const float* __restrict__ emb_j,
    const int* __restrict__ tags, const int* __restrict__ docs,
    bf16_t* __restrict__ Z, int* __restrict__ keys,
    float* __restrict__ denom, float* __restrict__ pair, int* __restrict__ cnt)
{
  __shared__ float4 zbuf[4][64];
  const int t = threadIdx.x;
  const int lane = t & 63, w = t >> 6;
  const int b = blockIdx.x;                     // 2048 blocks
  const int rlocal = 2 * b + (w & 1);
  const int row = rlocal + (w >> 1) * B_ROWS;
  const float* src = (w >> 1) ? (emb_j + (size_t)rlocal * D_DIM)
                              : (emb_i + (size_t)rlocal * D_DIM);
  float4 v = *(const float4*)(src + lane * 4);
  float ss = v.x * v.x + v.y * v.y + v.z * v.z + v.w * v.w;
  #pragma unroll
  for (int m = 32; m; m >>= 1) ss += __shfl_xor(ss, m, 64);
  float inv = 1.0f / sqrtf(ss);
  float4 z = {v.x * inv, v.y * inv, v.z * inv, v.w * inv};
  zbuf[w][lane] = z;

  bf16x4 q;
  q[0] = (bf16_t)z.x; q[1] = (bf16_t)z.y; q[2] = (bf16_t)z.z; q[3] = (bf16_t)z.w;
  *(bf16x4*)(Z + (size_t)row * D_DIM + lane * 4) = q;   // plain row-major

  if (lane == 0) {
    keys[row] = (tags[rlocal] << 16) | docs[rlocal];  // tag<100 (7b) | doc<512 (9b)
    denom[row] = 0.f;
  }
  if (b == 0 && t == 0) cnt[0] = 0;
  __syncthreads();
  if (w < 2) {  // pair dot from fp32 z (pre-rounding)
    float4 a = zbuf[w][lane], c = zbuf[w + 2][lane];
    float d = a.x * c.x + a.y * c.y + a.z * c.z + a.w * c.w;
    #pragma unroll
    for (int m = 32; m; m >>= 1) d += __shfl_xor(d, m, 64);
    if (lane == 0) pair[2 * b + w] = d;
  }
}

// ---------------- kernel 2: 256x256 tiles, BK=32 4-slot counted-vmcnt pipeline ----------------
#define BM   256
#define NRT  (TWOB / BM)            // 32 row tiles
#define NTIL (NRT * (NRT + 1) / 2)  // 528 triangle tiles
#define NBLK 256                    // tiles: {bid, bid+256, +512 if bid<16}
#define SLOTE 16384                 // elems per slot: A[256][32] + B[256][32]

__global__ __launch_bounds__(512, 2) void fused_kernel(
    const bf16_t* __restrict__ Z, const int* __restrict__ keys,
    float* __restrict__ denom, const float* __restrict__ pair,
    int* __restrict__ cnt, float* __restrict__ out)
{
  __shared__ bf16_t sL[4 * SLOTE];    // 4 x 32 KB ring
  __shared__ int s_last;
  __shared__ float s_red[8];
  const int tid  = threadIdx.x;
  const int lane = tid & 63;
  const int w    = tid >> 6;          // 8 waves
  const int wr = w >> 2, wc = w & 3;  // 2x4 wave grid; per-wave output 128x64
  const int l15 = lane & 15, l4 = lane >> 4;

  const int bid = blockIdx.x;         // no XCD swizzle: Z fits per-XCD L2; keeps
                                      // the 16 heavy (3-tile) blocks spread mod 8
  auto decode = [](int t, int& rt, int& ct) {
    int r = (int)((sqrtf(8.0f * (float)t + 1.0f) - 1.0f) * 0.5f);
    while ((r + 1) * (r + 2) / 2 <= t) ++r;
    while (r * (r + 1) / 2 > t) --r;
    rt = r; ct = t - r * (r + 1) / 2;
  };
  const bool has3 = (bid < NTIL - 2 * NBLK);   // bid < 16
  int rt, ct;
  decode(bid, rt, ct);
  const int r0a = rt * BM, c0a = ct * BM; const bool oda = (rt != ct);
  decode(bid + NBLK, rt, ct);
  const int r0b = rt * BM, c0b = ct * BM; const bool odb = (rt != ct);
  int r0c = 0, c0c = 0; bool odc = false;
  if (has3) { decode(bid + 2 * NBLK, rt, ct); r0c = rt * BM; c0c = ct * BM; odc = (rt != ct); }
  const int NT = has3 ? 24 : 16;      // 8 K-steps (BK=32) per tile

  f32x4 acc[8][4];
  const f32x4 vzero = {0.f, 0.f, 0.f, 0.f};
  #pragma unroll
  for (int mi = 0; mi < 8; ++mi)
    #pragma unroll
    for (int ni = 0; ni < 4; ++ni) acc[mi][ni] = vzero;

  // Fragment LDS offsets (elems). Read-side XOR (l4 ^ ((row>>1)&3)) pairs with
  // the inverse applied in STAGE's source address -> 2-way bank alias (free).
  const int swq   = (l15 >> 1) & 3;
  const int afoff = (wr * 128 + l15) * 32 + ((l4 ^ swq) * 8);
  const int bfoff = 8192 + (wc * 64 + l15) * 32 + ((l4 ^ swq) * 8);

  // stage K-step t's A+B 256x32 panels into slot (t&3): 4 x 16B per thread
  auto STAGE = [&](int t) {
    const int ti = t >> 3, kt = t & 7;
    const int row0 = (ti == 0) ? r0a : (ti == 1) ? r0b : r0c;
    const int col0 = (ti == 0) ? c0a : (ti == 1) ? c0b : c0c;
    const int slotB = (t & 3) * (SLOTE * 2);   // bytes
    #pragma unroll
    for (int i = 0; i < 4; ++i) {
      int o   = i * 8192 + tid * 16;           // byte offset in slot
      int isB = o >> 14;
      int rl  = (o & 16383) >> 6;              // panel row 0..255
      int p   = (o >> 4) & 3;                  // dest 16B group
      int q   = p ^ ((rl >> 1) & 3);           // source logical group
      int pr  = (isB ? col0 : row0) + rl;
      const bf16_t* g = Z + (size_t)pr * D_DIM + kt * 32 + q * 8;
      __builtin_amdgcn_global_load_lds(
          (const __attribute__((address_space(1))) void*)g,
          (__attribute__((address_space(3))) void*)((char*)sL + slotB + o), 16, 0, 0);
    }
  };

  auto EPI = [&](int ti) {
    const int row0 = (ti == 0) ? r0a : (ti == 1) ? r0b : r0c;
    const int col0 = (ti == 0) ? c0a : (ti == 1) ? c0b : c0c;
    const bool od  = (ti == 0) ? oda : (ti == 1) ? odb : odc;
    int keyc[4];
    #pragma unroll
    for (int ni = 0; ni < 4; ++ni)
      keyc[ni] = keys[col0 + wc * 64 + ni * 16 + l15];
    float colsum[4] = {0.f, 0.f, 0.f, 0.f};
    #pragma unroll
    for (int mi = 0; mi < 8; ++mi) {
      int keyr[4];
      #pragma unroll
      for (int j = 0; j < 4; ++j)
        keyr[j] = keys[row0 + wr * 128 + mi * 16 + l4 * 4 + j];
      float rowsum[4] = {0.f, 0.f, 0.f, 0.f};
      #pragma unroll
      for (int ni = 0; ni < 4; ++ni) {
        #pragma unroll
        for (int j = 0; j < 4; ++j) {
          int x = keyr[j] ^ keyc[ni];
          bool m = ((x >> 16) != 0) & ((x & 0xFFFF) != 0);
          float e = m ? __builtin_amdgcn_exp2f(acc[mi][ni][j] * kScale) : 0.f;
          rowsum[j] += e;
          colsum[ni] += e;
        }
        acc[mi][ni] = vzero;                   // reset for next tile
      }
      #pragma unroll
      for (int j = 0; j < 4; ++j) {
        float v = rowsum[j];
        v += __shfl_xor(v, 1, 64);
        v += __shfl_xor(v, 2, 64);
        v += __shfl_xor(v, 4, 64);
        v += __shfl_xor(v, 8, 64);
        if (l15 == 0)
          atomicAdd(&denom[row0 + wr * 128 + mi * 16 + l4 * 4 + j], v);
      }
    }
    if (od) {
      #pragma unroll
      for (int ni = 0; ni < 4; ++ni) {
        float v = colsum[ni];
        v += __shfl_xor(v, 16, 64);
        v += __shfl_xor(v, 32, 64);
        if (l4 == 0)
          atomicAdd(&denom[col0 + wc * 64 + ni * 16 + l15], v);
      }
    }
  };

  // ---- counted-vmcnt ring pipeline ----
  // Gate t: wait K-step t's 4 loads (vmcnt(8) leaves t+1,t+2 = 8 in flight),
  // barrier publishes all waves' staging; then stage t+3 into freed slot.
  // EPI traffic (key loads/atomics) only adds to outstanding -> gates get
  // stricter, never unsafe.
  STAGE(0); STAGE(1); STAGE(2);
  for (int t = 0; t < NT; ++t) {
    const int rem = NT - 1 - t;
    if (rem >= 2)      asm volatile("s_waitcnt vmcnt(8)" ::: "memory");
    else if (rem == 1) asm volatile("s_waitcnt vmcnt(4)" ::: "memory");
    else               asm volatile("s_waitcnt vmcnt(0)" ::: "memory");
    __builtin_amdgcn_s_barrier();
    __builtin_amdgcn_sched_barrier(0);
    if (t + 3 < NT) STAGE(t + 3);

    const int slotE = (t & 3) * SLOTE;
    bf16x8 af[8], bf[4];
    #pragma unroll
    for (int ni = 0; ni < 4; ++ni)
      bf[ni] = *(const bf16x8*)(sL + slotE + bfoff + ni * 512);
    #pragma unroll
    for (int mi = 0; mi < 8; ++mi)
      af[mi] = *(const bf16x8*)(sL + slotE + afoff + mi * 512);

    __builtin_amdgcn_s_setprio(1);
    #pragma unroll
    for (int mi = 0; mi < 8; ++mi)
      #pragma unroll
      for (int ni = 0; ni < 4; ++ni)
        acc[mi][ni] = __builtin_amdgcn_mfma_f32_16x16x32_bf16(
            af[mi], bf[ni], acc[mi][ni], 0, 0, 0);
    __builtin_amdgcn_s_setprio(0);

    if ((t & 7) == 7) EPI(t >> 3);             // overlaps in-flight staging
  }

  // ---- completion: last block computes the final loss ----
  __syncthreads();                             // drains this block's atomics
  if (tid == 0) {
    int done = __hip_atomic_fetch_add(cnt, 1, __ATOMIC_ACQ_REL, __HIP_MEMORY_SCOPE_AGENT);
    s_last = (done == NBLK - 1) ? 1 : 0;
  }
  __syncthreads();
  if (s_last) {
    float c = 0.f;
    #pragma unroll
    for (int i = 0; i < 16; ++i) {
      float d = __hip_atomic_load(&denom[i * 512 + tid], __ATOMIC_RELAXED,
                                  __HIP_MEMORY_SCOPE_AGENT);
      c += __logf(d + 0.1f);
    }
    #pragma unroll
    for (int i = 0; i < 8; ++i) c -= 4.0f * pair[i * 512 + tid];
    #pragma unroll
    for (int m = 32; m; m >>= 1) c += __shfl_xor(c, m, 64);
    if (lane == 0) s_red[w] = c;
    __syncthreads();
    if (tid == 0) {
      float s = 0.f;
      #pragma unroll
      for (int i = 0; i < 8; ++i) s += s_red[i];
      out[0] = s * (1.0f / (float)TWOB);
    }
  }
}

extern "C" void kernel_launch(void* const* d_in, const int* in_sizes, int n_in,
                              void* d_out, int out_size, void* d_ws, size_t ws_size,
                              hipStream_t stream) {
  const float* emb_i = (const float*)d_in[0];
  const float* emb_j = (const float*)d_in[1];
  const int*   tags  = (const int*)d_in[2];
  // d_in[3] = num_classes (unused)
  const int*   docs  = (const int*)d_in[4];

  char* ws = (char*)d_ws;
  bf16_t* Z     = (bf16_t*)(ws + WS_Z);
  int*    keys  = (int*)(ws + WS_KEYS);
  float*  denom = (float*)(ws + WS_DEN);
  float*  pair  = (float*)(ws + WS_PAIR);
  int*    cnt   = (int*)(ws + WS_CNT);
  float*  out   = (float*)d_out;

  prep_kernel<<<B_ROWS / 2, 256, 0, stream>>>(emb_i, emb_j, tags, docs, Z, keys, denom, pair, cnt);
  fused_kernel<<<NBLK, 512, 0, stream>>>(Z, keys, denom, pair, cnt, out);
}

// Round 12
// 125.600 us; speedup vs baseline: 5.3143x; 5.3143x over previous
//
#include <hip/hip_runtime.h>
#include <hip/hip_bf16.h>
#include <cstdint>
#include <cstddef>

#define B_ROWS 4096
#define D_DIM  256
#define TWOB   8192
static constexpr float kScale = 2.8853900817779268f; // log2(e)/TEMPERATURE, T=0.5

typedef __bf16 bf16_t;
typedef __bf16 bf16x4 __attribute__((ext_vector_type(4)));
typedef __bf16 bf16x8 __attribute__((ext_vector_type(8)));
typedef float  f32x4  __attribute__((ext_vector_type(4)));

// ---- workspace layout ----
#define WS_Z    0ull                                  // bf16 [8192][256], PLAIN row-major
#define WS_KEYS ((size_t)TWOB * D_DIM * 2)            // i32 [8192]
#define WS_DEN  (WS_KEYS + (size_t)TWOB * 4)          // f32 [8192]
#define WS_PAIR (WS_DEN + (size_t)TWOB * 4)           // f32 [4096]
#define WS_CNT  (WS_PAIR + (size_t)B_ROWS * 4)        // i32 [1]

// ---------------- kernel 1: normalize + bf16 store + keys + zeroing + pair dots ----------------
__global__ __launch_bounds__(256) void prep_kernel(
    const float* __restrict__ emb_i, const float* __restrict__ emb_j,
    const int* __restrict__ tags, const int* __restrict__ docs,
    bf16_t* __restrict__ Z, int* __restrict__ keys,
    float* __restrict__ denom, float* __restrict__ pair, int* __restrict__ cnt)
{
  __shared__ float4 zbuf[4][64];
  const int t = threadIdx.x;
  const int lane = t & 63, w = t >> 6;
  const int b = blockIdx.x;                     // 2048 blocks
  const int rlocal = 2 * b + (w & 1);
  const int row = rlocal + (w >> 1) * B_ROWS;
  const float* src = (w >> 1) ? (emb_j + (size_t)rlocal * D_DIM)
                              : (emb_i + (size_t)rlocal * D_DIM);
  float4 v = *(const float4*)(src + lane * 4);
  float ss = v.x * v.x + v.y * v.y + v.z * v.z + v.w * v.w;
  #pragma unroll
  for (int m = 32; m; m >>= 1) ss += __shfl_xor(ss, m, 64);
  float inv = 1.0f / sqrtf(ss);
  float4 z = {v.x * inv, v.y * inv, v.z * inv, v.w * inv};
  zbuf[w][lane] = z;

  bf16x4 q;
  q[0] = (bf16_t)z.x; q[1] = (bf16_t)z.y; q[2] = (bf16_t)z.z; q[3] = (bf16_t)z.w;
  *(bf16x4*)(Z + (size_t)row * D_DIM + lane * 4) = q;   // plain row-major

  if (lane == 0) {
    keys[row] = (tags[rlocal] << 16) | docs[rlocal];  // tag<100 (7b) | doc<512 (9b)
    denom[row] = 0.f;
  }
  if (b == 0 && t == 0) cnt[0] = 0;
  __syncthreads();
  if (w < 2) {  // pair dot from fp32 z (pre-rounding)
    float4 a = zbuf[w][lane], c = zbuf[w + 2][lane];
    float d = a.x * c.x + a.y * c.y + a.z * c.z + a.w * c.w;
    #pragma unroll
    for (int m = 32; m; m >>= 1) d += __shfl_xor(d, m, 64);
    if (lane == 0) pair[2 * b + w] = d;
  }
}

// ---------------- kernel 2: 256x256 tiles, BK=32 4-slot ring, counted vmcnt, FULLY UNROLLED ----------------
#define BM   256
#define NRT  (TWOB / BM)            // 32 row tiles
#define NTIL (NRT * (NRT + 1) / 2)  // 528 triangle tiles
#define NBLK 256                    // tiles: {bid, bid+256, +512 if bid<16}
#define SLOTE 16384                 // elems per slot: A[256][32] + B[256][32]

__global__ __launch_bounds__(512, 1) void fused_kernel(
    const bf16_t* __restrict__ Z, const int* __restrict__ keys,
    float* __restrict__ denom, const float* __restrict__ pair,
    int* __restrict__ cnt, float* __restrict__ out)
{
  __shared__ bf16_t sL[4 * SLOTE];    // 4 x 32 KB ring
  __shared__ int s_last;
  __shared__ float s_red[8];
  const int tid  = threadIdx.x;
  const int lane = tid & 63;
  const int w    = tid >> 6;          // 8 waves
  const int wr = w >> 2, wc = w & 3;  // 2x4 wave grid; per-wave output 128x64
  const int l15 = lane & 15, l4 = lane >> 4;

  const int bid = blockIdx.x;         // no XCD swizzle: heavy (3-tile) blocks stay spread mod 8
  auto decode = [](int t, int& rt, int& ct) {
    int r = (int)((sqrtf(8.0f * (float)t + 1.0f) - 1.0f) * 0.5f);
    while ((r + 1) * (r + 2) / 2 <= t) ++r;
    while (r * (r + 1) / 2 > t) --r;
    rt = r; ct = t - r * (r + 1) / 2;
  };
  const bool has3 = (bid < NTIL - 2 * NBLK);   // bid < 16
  int rt, ct;
  decode(bid, rt, ct);
  const int r0a = rt * BM, c0a = ct * BM; const bool oda = (rt != ct);
  decode(bid + NBLK, rt, ct);
  const int r0b = rt * BM, c0b = ct * BM; const bool odb = (rt != ct);
  int r0c = 0, c0c = 0; bool odc = false;
  if (has3) { decode(bid + 2 * NBLK, rt, ct); r0c = rt * BM; c0c = ct * BM; odc = (rt != ct); }

  f32x4 acc[8][4];
  const f32x4 vzero = {0.f, 0.f, 0.f, 0.f};
  #pragma unroll
  for (int mi = 0; mi < 8; ++mi)
    #pragma unroll
    for (int ni = 0; ni < 4; ++ni) acc[mi][ni] = vzero;

  // Fragment LDS offsets (elems). Read-side XOR (l4 ^ ((row>>1)&3)) pairs with
  // the inverse in STAGE's source address -> 2-way bank alias (free, m136).
  const int swq   = (l15 >> 1) & 3;
  const int afoff = (wr * 128 + l15) * 32 + ((l4 ^ swq) * 8);
  const int bfoff = 8192 + (wc * 64 + l15) * 32 + ((l4 ^ swq) * 8);

  // stage A+B 256x32 panels of K-step kt into slot: 4 x 16B per thread.
  // kt and slot are COMPILE-TIME constants at every call site (unrolled).
  auto STAGE = [&](int row0, int col0, int kt, int slot) {
    const int slotB = slot * (SLOTE * 2);      // bytes
    #pragma unroll
    for (int i = 0; i < 4; ++i) {
      int o   = i * 8192 + tid * 16;           // byte offset in slot
      int isB = o >> 14;
      int rl  = (o & 16383) >> 6;              // panel row 0..255
      int p   = (o >> 4) & 3;                  // dest 16B group
      int q   = p ^ ((rl >> 1) & 3);           // source logical group
      int pr  = (isB ? col0 : row0) + rl;
      const bf16_t* g = Z + (size_t)pr * D_DIM + kt * 32 + q * 8;
      __builtin_amdgcn_global_load_lds(
          (const __attribute__((address_space(1))) void*)g,
          (__attribute__((address_space(3))) void*)((char*)sL + slotB + o), 16, 0, 0);
    }
  };

  auto EPI = [&](int row0, int col0, bool od) {
    int keyc[4];
    #pragma unroll
    for (int ni = 0; ni < 4; ++ni)
      keyc[ni] = keys[col0 + wc * 64 + ni * 16 + l15];
    float colsum[4] = {0.f, 0.f, 0.f, 0.f};
    #pragma unroll
    for (int mi = 0; mi < 8; ++mi) {
      int keyr[4];
      #pragma unroll
      for (int j = 0; j < 4; ++j)
        keyr[j] = keys[row0 + wr * 128 + mi * 16 + l4 * 4 + j];
      float rowsum[4] = {0.f, 0.f, 0.f, 0.f};
      #pragma unroll
      for (int ni = 0; ni < 4; ++ni) {
        #pragma unroll
        for (int j = 0; j < 4; ++j) {
          int x = keyr[j] ^ keyc[ni];
          bool m = ((x >> 16) != 0) & ((x & 0xFFFF) != 0);
          float e = m ? __builtin_amdgcn_exp2f(acc[mi][ni][j] * kScale) : 0.f;
          rowsum[j] += e;
          colsum[ni] += e;
        }
        acc[mi][ni] = vzero;                   // reset for next tile
      }
      #pragma unroll
      for (int j = 0; j < 4; ++j) {
        float v = rowsum[j];
        v += __shfl_xor(v, 1, 64);
        v += __shfl_xor(v, 2, 64);
        v += __shfl_xor(v, 4, 64);
        v += __shfl_xor(v, 8, 64);
        if (l15 == 0)
          atomicAdd(&denom[row0 + wr * 128 + mi * 16 + l4 * 4 + j], v);
      }
    }
    if (od) {
      #pragma unroll
      for (int ni = 0; ni < 4; ++ni) {
        float v = colsum[ni];
        v += __shfl_xor(v, 16, 64);
        v += __shfl_xor(v, 32, 64);
        if (l4 == 0)
          atomicAdd(&denom[col0 + wc * 64 + ni * 16 + l15], v);
      }
    }
  };

  // One tile = 8 K-steps through the 4-slot ring, counted gates, fully unrolled.
  // Gate kt: kt's 4 loads done; kt+1/kt+2 (8 loads) stay in flight. After the
  // gate+barrier, STAGE(kt+3) refills the slot freed by kt-1... ring invariant:
  // slot s is re-written only after the barrier that retired all reads of s.
  auto TILE = [&](int row0, int col0, bool od, bool don, int nr, int nc) {
    #pragma unroll
    for (int kt = 0; kt < 8; ++kt) {
      if (kt <= 5)      asm volatile("s_waitcnt vmcnt(8)" ::: "memory");
      else if (kt == 6) asm volatile("s_waitcnt vmcnt(4)" ::: "memory");
      else              asm volatile("s_waitcnt vmcnt(0)" ::: "memory");
      __builtin_amdgcn_s_barrier();
      __builtin_amdgcn_sched_barrier(0);
      if (kt < 5) STAGE(row0, col0, kt + 3, (kt + 3) & 3);

      const int slotE = (kt & 3) * SLOTE;
      bf16x8 af[8], bf[4];
      #pragma unroll
      for (int ni = 0; ni < 4; ++ni)
        bf[ni] = *(const bf16x8*)(sL + slotE + bfoff + ni * 512);
      #pragma unroll
      for (int mi = 0; mi < 8; ++mi)
        af[mi] = *(const bf16x8*)(sL + slotE + afoff + mi * 512);

      __builtin_amdgcn_s_setprio(1);
      #pragma unroll
      for (int mi = 0; mi < 8; ++mi)
        #pragma unroll
        for (int ni = 0; ni < 4; ++ni)
          acc[mi][ni] = __builtin_amdgcn_mfma_f32_16x16x32_bf16(
              af[mi], bf[ni], acc[mi][ni], 0, 0, 0);
      __builtin_amdgcn_s_setprio(0);
    }
    EPI(row0, col0, od);
    if (don) {  // next tile's 3-step prologue (slots 0..2 free since kt=4..6 reads)
      STAGE(nr, nc, 0, 0);
      STAGE(nr, nc, 1, 1);
      STAGE(nr, nc, 2, 2);
    }
  };

  // prologue tile A
  STAGE(r0a, c0a, 0, 0);
  STAGE(r0a, c0a, 1, 1);
  STAGE(r0a, c0a, 2, 2);
  TILE(r0a, c0a, oda, true, r0b, c0b);
  TILE(r0b, c0b, odb, has3, r0c, c0c);
  if (has3) TILE(r0c, c0c, odc, false, 0, 0);

  // ---- completion: last block computes the final loss ----
  __syncthreads();                             // drains this block's atomics
  if (tid == 0) {
    int done = __hip_atomic_fetch_add(cnt, 1, __ATOMIC_ACQ_REL, __HIP_MEMORY_SCOPE_AGENT);
    s_last = (done == NBLK - 1) ? 1 : 0;
  }
  __syncthreads();
  if (s_last) {
    float c = 0.f;
    #pragma unroll
    for (int i = 0; i < 16; ++i) {
      float d = __hip_atomic_load(&denom[i * 512 + tid], __ATOMIC_RELAXED,
                                  __HIP_MEMORY_SCOPE_AGENT);
      c += __logf(d + 0.1f);
    }
    #pragma unroll
    for (int i = 0; i < 8; ++i) c -= 4.0f * pair[i * 512 + tid];
    #pragma unroll
    for (int m = 32; m; m >>= 1) c += __shfl_xor(c, m, 64);
    if (lane == 0) s_red[w] = c;
    __syncthreads();
    if (tid == 0) {
      float s = 0.f;
      #pragma unroll
      for (int i = 0; i < 8; ++i) s += s_red[i];
      out[0] = s * (1.0f / (float)TWOB);
    }
  }
}

extern "C" void kernel_launch(void* const* d_in, const int* in_sizes, int n_in,
                              void* d_out, int out_size, void* d_ws, size_t ws_size,
                              hipStream_t stream) {
  const float* emb_i = (const float*)d_in[0];
  const float* emb_j = (const float*)d_in[1];
  const int*   tags  = (const int*)d_in[2];
  // d_in[3] = num_classes (unused)
  const int*   docs  = (const int*)d_in[4];

  char* ws = (char*)d_ws;
  bf16_t* Z     = (bf16_t*)(ws + WS_Z);
  int*    keys  = (int*)(ws + WS_KEYS);
  float*  denom = (float*)(ws + WS_DEN);
  float*  pair  = (float*)(ws + WS_PAIR);
  int*    cnt   = (int*)(ws + WS_CNT);
  float*  out   = (float*)d_out;

  prep_kernel<<<B_ROWS / 2, 256, 0, stream>>>(emb_i, emb_j, tags, docs, Z, keys, denom, pair, cnt);
  fused_kernel<<<NBLK, 512, 0, stream>>>(Z, keys, denom, pair, cnt, out);
}